// Round 1
// baseline (733.344 us; speedup 1.0000x reference)
//
#include <hip/hip_runtime.h>
#include <math.h>

#define NUM_EMB 8192
#define DIM     64
#define NBATCH  4
#define NVOX    32768
#define TPB     256
#define SPLIT   8                 // codebook splits per voxel-block
#define EPB     (NUM_EMB / SPLIT) // 1024 entries per split
#define CHUNK   128               // entries staged in LDS per iteration

// output layout (f32, concatenated in return order)
#define OFF_Q     0            // 32768*64
#define OFF_VQ    2097152
#define OFF_COMM  2097153
#define OFF_IDX   2097154      // 32768
#define OFF_PERP  2129922
#define OFF_ENT   2129923
#define OFF_UNIQ  2129924
#define OFF_UTIL  2129925

// monotone float -> sortable uint (all non-NaN)
__device__ __forceinline__ unsigned fmap(float f) {
    unsigned u = __float_as_uint(f);
    return (u & 0x80000000u) ? ~u : (u | 0x80000000u);
}

__global__ void cnorm_kernel(const float* __restrict__ cb, float* __restrict__ cn) {
    int e = blockIdx.x * blockDim.x + threadIdx.x;
    const float4* row = (const float4*)(cb + (size_t)e * DIM);
    float s = 0.f;
#pragma unroll
    for (int i = 0; i < DIM / 4; ++i) {
        float4 v = row[i];
        s += v.x * v.x + v.y * v.y + v.z * v.z + v.w * v.w;
    }
    cn[e] = s;
}

__global__ __launch_bounds__(TPB, 4) void argmin_kernel(
        const float* __restrict__ z, const float* __restrict__ cb,
        const float* __restrict__ cn, unsigned long long* __restrict__ merge) {
    __shared__ float lcb[CHUNK * DIM];
    __shared__ float lcn[CHUNK];

    int vb  = blockIdx.x / SPLIT;   // voxel block 0..127
    int sp  = blockIdx.x % SPLIT;   // codebook split 0..7
    int vox = vb * TPB + threadIdx.x;

    float zr[DIM];
    const float4* zrow = (const float4*)(z + (size_t)vox * DIM);
#pragma unroll
    for (int i = 0; i < DIM / 4; ++i) {
        float4 v = zrow[i];
        zr[4 * i + 0] = v.x; zr[4 * i + 1] = v.y;
        zr[4 * i + 2] = v.z; zr[4 * i + 3] = v.w;
    }

    float best = INFINITY;
    int   bidx = 0;
    const int ebase = sp * EPB;

    for (int c = 0; c < EPB; c += CHUNK) {
        // cooperative stage: CHUNK rows -> LDS (coalesced float4)
        const float4* src = (const float4*)(cb + (size_t)(ebase + c) * DIM);
        float4* dst = (float4*)lcb;
#pragma unroll
        for (int i = 0; i < (CHUNK * DIM / 4) / TPB; ++i)   // 8 per thread
            dst[i * TPB + threadIdx.x] = src[i * TPB + threadIdx.x];
        if (threadIdx.x < CHUNK) lcn[threadIdx.x] = cn[ebase + c + threadIdx.x];
        __syncthreads();

        for (int e = 0; e < CHUNK; ++e) {
            const float4* crow = (const float4*)(lcb + e * DIM);
            float a0 = 0.f, a1 = 0.f, a2 = 0.f, a3 = 0.f;
#pragma unroll
            for (int i = 0; i < DIM / 4; ++i) {
                float4 c4 = crow[i];             // wave-uniform LDS broadcast
                a0 = fmaf(c4.x, zr[4 * i + 0], a0);
                a1 = fmaf(c4.y, zr[4 * i + 1], a1);
                a2 = fmaf(c4.z, zr[4 * i + 2], a2);
                a3 = fmaf(c4.w, zr[4 * i + 3], a3);
            }
            float dist = lcn[e] - 2.f * ((a0 + a1) + (a2 + a3));
            if (dist < best) { best = dist; bidx = ebase + c + e; }
        }
        __syncthreads();
    }

    unsigned long long key = ((unsigned long long)fmap(best) << 32) | (unsigned)bidx;
    atomicMin(&merge[vox], key);
}

__global__ void gather_kernel(const float* __restrict__ z, const int* __restrict__ zc,
        const float* __restrict__ cb, const unsigned long long* __restrict__ merge,
        float* __restrict__ out, unsigned* __restrict__ counts, float* __restrict__ sqsum) {
    int vox = blockIdx.x * blockDim.x + threadIdx.x;
    unsigned idx = (unsigned)(merge[vox] & 0xFFFFFFFFull);

    const float4* crow = (const float4*)(cb + (size_t)idx * DIM);
    const float4* zrow = (const float4*)(z + (size_t)vox * DIM);
    float4* qrow = (float4*)(out + OFF_Q + (size_t)vox * DIM);

    float s = 0.f;
#pragma unroll
    for (int i = 0; i < DIM / 4; ++i) {
        float4 c4 = crow[i];
        float4 z4 = zrow[i];
        float dx = z4.x - c4.x, dy = z4.y - c4.y;
        float dz = z4.z - c4.z, dw = z4.w - c4.w;
        s += dx * dx + dy * dy + dz * dz + dw * dw;
        qrow[i] = c4;
    }
    out[OFF_IDX + vox] = (float)idx;

    int b = zc[vox * 4];
    atomicAdd(&counts[b * NUM_EMB + idx], 1u);

    // block-reduce s, one float atomicAdd per block
#pragma unroll
    for (int o = 32; o > 0; o >>= 1) s += __shfl_down(s, o, 64);
    __shared__ float red[TPB / 64];
    if ((threadIdx.x & 63) == 0) red[threadIdx.x >> 6] = s;
    __syncthreads();
    if (threadIdx.x == 0) {
        float t = red[0] + red[1] + red[2] + red[3];
        atomicAdd(sqsum, t);
    }
}

__global__ void stats_kernel(const unsigned* __restrict__ counts, float* __restrict__ stats) {
    int b = blockIdx.x;
    const unsigned* c = counts + b * NUM_EMB;

    __shared__ float sred[TPB / 64];
    // pass 1: n = total count for this batch
    float nf = 0.f;
    for (int i = threadIdx.x; i < NUM_EMB; i += TPB) nf += (float)c[i];
#pragma unroll
    for (int o = 32; o > 0; o >>= 1) nf += __shfl_down(nf, o, 64);
    if ((threadIdx.x & 63) == 0) sred[threadIdx.x >> 6] = nf;
    __syncthreads();
    float n = sred[0] + sred[1] + sred[2] + sred[3];
    __syncthreads();

    // pass 2: entropy & unique
    float ent = 0.f, uniq = 0.f;
    for (int i = threadIdx.x; i < NUM_EMB; i += TPB) {
        unsigned ci = c[i];
        if (ci) {
            float p = (float)ci / n;
            ent -= p * logf(p + 1e-10f);
            uniq += 1.f;
        }
    }
#pragma unroll
    for (int o = 32; o > 0; o >>= 1) {
        ent  += __shfl_down(ent, o, 64);
        uniq += __shfl_down(uniq, o, 64);
    }
    __shared__ float e4[TPB / 64], u4[TPB / 64];
    if ((threadIdx.x & 63) == 0) { e4[threadIdx.x >> 6] = ent; u4[threadIdx.x >> 6] = uniq; }
    __syncthreads();
    if (threadIdx.x == 0) {
        stats[b]     = e4[0] + e4[1] + e4[2] + e4[3];
        stats[4 + b] = u4[0] + u4[1] + u4[2] + u4[3];
    }
}

__global__ void finalize_kernel(const float* __restrict__ stats,
                                const float* __restrict__ sqsum,
                                float* __restrict__ out) {
    float loss = *sqsum / (float)((size_t)NVOX * DIM);
    float ae = 0.f, ap = 0.f, au = 0.f;
#pragma unroll
    for (int b = 0; b < NBATCH; ++b) {
        ae += stats[b];
        ap += expf(stats[b]);
        au += stats[4 + b];
    }
    ae *= (1.f / NBATCH); ap *= (1.f / NBATCH); au *= (1.f / NBATCH);
    out[OFF_VQ]   = loss;
    out[OFF_COMM] = loss;
    out[OFF_PERP] = ap;
    out[OFF_ENT]  = ae;
    out[OFF_UNIQ] = au;
    out[OFF_UTIL] = au / (float)NUM_EMB * 100.f;
}

extern "C" void kernel_launch(void* const* d_in, const int* in_sizes, int n_in,
                              void* d_out, int out_size, void* d_ws, size_t ws_size,
                              hipStream_t stream) {
    const float* z  = (const float*)d_in[0];
    const int*   zc = (const int*)d_in[1];
    const float* cb = (const float*)d_in[2];
    float* out = (float*)d_out;
    char* ws = (char*)d_ws;

    unsigned long long* merge = (unsigned long long*)ws;        // 32768*8 = 262144 B
    unsigned* counts = (unsigned*)(ws + 262144);                // 4*8192*4 = 131072 B
    float* cn    = (float*)(ws + 393216);                       // 8192*4 = 32768 B
    float* sqsum = (float*)(ws + 425984);                       // 4 B
    float* stats = (float*)(ws + 425988);                       // 8*4 = 32 B

    hipMemsetAsync(merge, 0xFF, 262144, stream);                // u64 max sentinel
    hipMemsetAsync(counts, 0, 131072 + 32768 + 4 + 32, stream); // counts/cn/sqsum/stats

    cnorm_kernel<<<NUM_EMB / TPB, TPB, 0, stream>>>(cb, cn);
    argmin_kernel<<<(NVOX / TPB) * SPLIT, TPB, 0, stream>>>(z, cb, cn, merge);
    gather_kernel<<<NVOX / TPB, TPB, 0, stream>>>(z, zc, cb, merge, out, counts, sqsum);
    stats_kernel<<<NBATCH, TPB, 0, stream>>>(counts, stats);
    finalize_kernel<<<1, 1, 0, stream>>>(stats, sqsum, out);
}